// Round 4
// baseline (886.621 us; speedup 1.0000x reference)
//
#include <hip/hip_runtime.h>
#include <hip/hip_fp16.h>
#include <math.h>

#define BB 1024
#define LSx 128
#define LLx 2048
#define TOPKx 48
#define VOCABx 160000

// ---------------------------------------------------------------------------
// Kernel A: precompute partial LSH projections (fp16 storage), thread per v.
//   Ph[v][seg][m] = sum_e emb[v][e] * H[seg*16+e][m]
// ---------------------------------------------------------------------------
__global__ __launch_bounds__(256) void k_partial(
    const float* __restrict__ emb, const float* __restrict__ Hm,
    __half* __restrict__ Ph)
{
  const int v = blockIdx.x * 256 + threadIdx.x;
  if (v >= VOCABx) return;
  const float4* er = (const float4*)(emb + (size_t)v * 16);
  const float4 x0 = er[0], x1 = er[1], x2 = er[2], x3 = er[3];
  const float x[16] = {x0.x, x0.y, x0.z, x0.w, x1.x, x1.y, x1.z, x1.w,
                       x2.x, x2.y, x2.z, x2.w, x3.x, x3.y, x3.z, x3.w};
  unsigned int packed[24];
  #pragma unroll
  for (int seg = 0; seg < 3; ++seg) {
    #pragma unroll
    for (int mp = 0; mp < 8; ++mp) {
      float a0 = 0.f, a1 = 0.f;
      #pragma unroll
      for (int e = 0; e < 16; ++e) {
        a0 += x[e] * Hm[(seg * 16 + e) * 16 + 2 * mp];
        a1 += x[e] * Hm[(seg * 16 + e) * 16 + 2 * mp + 1];
      }
      const __half2 hp = __floats2half2_rn(a0, a1);
      packed[seg * 8 + mp] = *(const unsigned int*)&hp;
    }
  }
  uint4* dst = (uint4*)(Ph + (size_t)v * 48);
  #pragma unroll
  for (int q = 0; q < 6; ++q) {
    uint4 o;
    o.x = packed[q * 4 + 0]; o.y = packed[q * 4 + 1];
    o.z = packed[q * 4 + 2]; o.w = packed[q * 4 + 3];
    dst[q] = o;
  }
}

// ---------------------------------------------------------------------------
// kv projection helper, 12-wide j slice. j0 must be an SGPR (readfirstlane).
// ---------------------------------------------------------------------------
__device__ __forceinline__ void kv12(
    const float* __restrict__ W, const float* __restrict__ bvec, int j0,
    int gid, int sid, int cid, const float* __restrict__ emb, float acc[12])
{
  #pragma unroll
  for (int j = 0; j < 12; ++j) acc[j] = bvec[j0 + j];
  const int ids3[3] = {gid, sid, cid};
  #pragma unroll
  for (int seg = 0; seg < 3; ++seg) {
    const float* row = emb + (size_t)ids3[seg] * 16;
    #pragma unroll
    for (int i4 = 0; i4 < 4; ++i4) {
      const float4 xv = ((const float4*)row)[i4];
      const float xs[4] = {xv.x, xv.y, xv.z, xv.w};
      #pragma unroll
      for (int c = 0; c < 4; ++c) {
        const float* wr = W + (seg * 16 + i4 * 4 + c) * 48 + j0;
        const float xe = xs[c];
        #pragma unroll
        for (int j = 0; j < 12; ++j) acc[j] += xe * wr[j];
      }
    }
  }
}

__device__ __forceinline__ void kv24(
    const float* __restrict__ W, const float* __restrict__ bvec, int j0,
    int gid, int sid, int cid, const float* __restrict__ emb, float acc[24])
{
  #pragma unroll
  for (int j = 0; j < 24; ++j) acc[j] = bvec[j0 + j];
  const int ids3[3] = {gid, sid, cid};
  #pragma unroll
  for (int seg = 0; seg < 3; ++seg) {
    const float* row = emb + (size_t)ids3[seg] * 16;
    #pragma unroll
    for (int i4 = 0; i4 < 4; ++i4) {
      const float4 xv = ((const float4*)row)[i4];
      const float xs[4] = {xv.x, xv.y, xv.z, xv.w};
      #pragma unroll
      for (int c = 0; c < 4; ++c) {
        const float* wr = W + (seg * 16 + i4 * 4 + c) * 48 + j0;
        const float xe = xs[c];
        #pragma unroll
        for (int j = 0; j < 24; ++j) acc[j] += xe * wr[j];
      }
    }
  }
}

// ---------------------------------------------------------------------------
// Kernel B (fused main): grid 2048 x 512.
//   bid <  1024: LSH score + top-k + long-MHA  -> lint
//   bid >= 1024: short-MHA                     -> sint
// ---------------------------------------------------------------------------
__global__ __launch_bounds__(512, 4) void k_main(
    const int* __restrict__ lg, const int* __restrict__ lsh, const int* __restrict__ lc,
    const int* __restrict__ sg, const int* __restrict__ ss, const int* __restrict__ scd,
    const int* __restrict__ ig, const int* __restrict__ ish, const int* __restrict__ ici,
    const float* __restrict__ emb, const float* __restrict__ Hm,
    const __half* __restrict__ Ph,
    const float* __restrict__ sWq, const float* __restrict__ sbq,
    const float* __restrict__ sWk, const float* __restrict__ sbk,
    const float* __restrict__ sWv, const float* __restrict__ sbv,
    const float* __restrict__ sWo, const float* __restrict__ sbo,
    const float* __restrict__ lWq, const float* __restrict__ lbq,
    const float* __restrict__ lWk, const float* __restrict__ lbk,
    const float* __restrict__ lWv, const float* __restrict__ lbv,
    const float* __restrict__ lWo, const float* __restrict__ lbo,
    float* __restrict__ sint, float* __restrict__ lint)
{
  __shared__ __align__(16) char pool[38912];
  const int bid = blockIdx.x, tid = threadIdx.x;
  const int lane = tid & 63, wave = tid >> 6;

  if (bid < BB) {
    // =================== score + top-k + long MHA =======================
    const int b = bid;
    int* idsL = (int*)pool;                               // 24576 B
    signed char* scores = (signed char*)(pool + 24576);   // 2048
    int* selL = (int*)(pool + 26624);                     // 192
    int* hist = (int*)(pool + 26816);                     // 72
    int* icodeS = (int*)(pool + 26896);                   // 64
    int* wsum = (int*)(pool + 26960);                     // 32
    int* cnt_above = (int*)(pool + 26992);                // 4
    float* Xitem = (float*)(pool + 27008);                // 192
    float* vhs = (float*)(pool + 27200);                  // 48*49*4 = 9408
    float* scs = (float*)(pool + 36608);                  // 8*52*4 = 1664
    float* qh = (float*)(pool + 38272);                   // 192
    float* osm = (float*)(pool + 38464);                  // 192
    unsigned char* validf = (unsigned char*)(pool + 38656); // 48

    ((int4*)idsL)[tid]        = ((const int4*)(lg  + (size_t)b * LLx))[tid];
    ((int4*)idsL)[512 + tid]  = ((const int4*)(lsh + (size_t)b * LLx))[tid];
    ((int4*)idsL)[1024 + tid] = ((const int4*)(lc  + (size_t)b * LLx))[tid];
    if (tid < 48) {
      const int seg = tid >> 4, e = tid & 15;
      const int id = (seg == 0) ? ig[b] : (seg == 1) ? ish[b] : ici[b];
      Xitem[tid] = emb[(size_t)id * 16 + e];
    }
    if (tid < 18) hist[tid] = 0;
    if (tid == 0) *cnt_above = 0;
    __syncthreads();
    if (tid < 16) {  // exact fp32 item code
      float dd = 0.f;
      for (int e = 0; e < 48; ++e) dd += Xitem[e] * Hm[e * 16 + tid];
      icodeS[tid] = (dd > 0.f) ? 1 : (dd < 0.f ? -1 : 0);
    }
    __syncthreads();

    const int l16 = tid & 15;
    const int grpw = (tid >> 4) & 3;
    const int grp32 = tid >> 4;
    const int myic = icodeS[l16];

    for (int r8 = 0; r8 < 64; r8 += 8) {
      int g_[8], s_[8], c_[8];
      #pragma unroll
      for (int u = 0; u < 8; ++u) {
        const int p = (r8 + u) * 32 + grp32;
        g_[u] = idsL[p]; s_[u] = idsL[LLx + p]; c_[u] = idsL[2 * LLx + p];
      }
      float d0[8], d1[8], d2[8];
      #pragma unroll
      for (int u = 0; u < 8; ++u) {
        d0[u] = __half2float(Ph[(size_t)g_[u] * 48 + l16]);
        d1[u] = __half2float(Ph[(size_t)s_[u] * 48 + 16 + l16]);
        d2[u] = __half2float(Ph[(size_t)c_[u] * 48 + 32 + l16]);
      }
      #pragma unroll
      for (int u = 0; u < 8; ++u) {
        const int p = (r8 + u) * 32 + grp32;
        const float d = (d0[u] + d1[u]) + d2[u];
        const int cs = (d > 0.f) ? 1 : (d < 0.f ? -1 : 0);
        const unsigned long long bal = __ballot(cs == myic);
        int sc = (int)__popcll((bal >> (16 * grpw)) & 0xFFFFull);
        if (g_[u] == 0) sc = -1;   // masked (reference: -inf)
        if (l16 == 0) {
          scores[p] = (signed char)sc;
          atomicAdd(&hist[sc + 1], 1);
        }
      }
    }
    __syncthreads();

    // ---- threshold (identical on all threads) ----
    int above = 0, tval = -1, need = 0;
    for (int s = 16; s >= -1; --s) {
      const int c = hist[s + 1];
      if (above + c >= TOPKx) { tval = s; need = TOPKx - above; break; }
      above += c;
    }

    // ---- tie ranking: 4 consecutive positions per thread + block scan ----
    const int base_l = tid * 4;
    int myscore[4];
    #pragma unroll
    for (int j = 0; j < 4; ++j) myscore[j] = scores[base_l + j];
    int cnt = 0;
    #pragma unroll
    for (int j = 0; j < 4; ++j) cnt += (myscore[j] == tval) ? 1 : 0;
    int v = cnt;
    #pragma unroll
    for (int o = 1; o < 64; o <<= 1) {
      const int u = __shfl_up(v, o, 64);
      if (lane >= o) v += u;
    }
    if (lane == 63) wsum[wave] = v;
    __syncthreads();
    int rank = v - cnt;
    for (int w = 0; w < wave; ++w) rank += wsum[w];

    #pragma unroll
    for (int j = 0; j < 4; ++j) {
      const int l = base_l + j;
      const int s = myscore[j];
      if (s > tval) {
        const int slot = atomicAdd(cnt_above, 1);
        selL[slot] = l;
      } else if (s == tval) {
        if (rank < need) selL[above + rank] = l;
        ++rank;
      }
    }
    __syncthreads();

    // =================== fused long-MHA over selL ======================
    // wave w: role = w>>2 (0=k,1=v), jq = w&3, p = lane (<48)
    const int role = wave >> 2;
    const int jq = wave & 3;
    const int p = lane;
    const bool act = (lane < 48);
    int gid = 0, sid = 0, cid = 0;
    if (act) {
      const int pos = selL[p];
      gid = idsL[pos]; sid = idsL[LLx + pos]; cid = idsL[2 * LLx + pos];
      if (tid < 48) validf[p] = (unsigned char)(gid != 0);
    }
    if (tid < 48) {
      float a = lbq[tid];
      for (int e = 0; e < 48; ++e) a += Xitem[e] * lWq[e * 48 + tid];
      qh[tid] = a;
    }
    const int j0 = __builtin_amdgcn_readfirstlane(jq * 12);
    float acc[12];
    if (role == 0) kv12(lWk, lbk, j0, gid, sid, cid, emb, acc);
    else           kv12(lWv, lbv, j0, gid, sid, cid, emb, acc);
    const int nval = __syncthreads_count(tid < 48 && gid != 0);

    if (act) {
      if (role == 0) {
        #pragma unroll
        for (int hh = 0; hh < 2; ++hh) {
          const int h = jq * 2 + hh;
          float s = 0.f;
          #pragma unroll
          for (int d = 0; d < 6; ++d) s += qh[h * 6 + d] * acc[hh * 6 + d];
          scs[h * 52 + p] = s * 0.40824829046386301637f;
        }
      } else {
        #pragma unroll
        for (int j = 0; j < 12; ++j) vhs[p * 49 + j0 + j] = acc[j];
      }
    }
    __syncthreads();

    if (tid < 128) {
      const int h = tid >> 4, l16b = tid & 15;
      float amax = -INFINITY;
      for (int k = l16b; k < TOPKx; k += 16) if (validf[k]) amax = fmaxf(amax, scs[h * 52 + k]);
      #pragma unroll
      for (int m = 1; m < 16; m <<= 1) amax = fmaxf(amax, __shfl_xor(amax, m, 16));
      if (nval == 0) {
        for (int k = l16b; k < TOPKx; k += 16) scs[h * 52 + k] = 1.0f / (float)TOPKx;
      } else {
        float ssum = 0.f;
        for (int k = l16b; k < TOPKx; k += 16) {
          const float ev = validf[k] ? expf(scs[h * 52 + k] - amax) : 0.f;
          scs[h * 52 + k] = ev;
          ssum += ev;
        }
        #pragma unroll
        for (int m = 1; m < 16; m <<= 1) ssum += __shfl_xor(ssum, m, 16);
        const float inv = 1.0f / ssum;
        for (int k = l16b; k < TOPKx; k += 16) scs[h * 52 + k] *= inv;
      }
    }
    __syncthreads();

    if (tid < 48) {
      const int h = tid / 6;
      float a = 0.f;
      for (int k = 0; k < TOPKx; ++k) a += scs[h * 52 + k] * vhs[k * 49 + tid];
      osm[tid] = a;
    }
    __syncthreads();
    if (tid < 48) {
      float r = lbo[tid];
      for (int j = 0; j < 48; ++j) r += osm[j] * lWo[j * 48 + tid];
      lint[b * 48 + tid] = r;
    }
  } else {
    // ========================= short MHA ===============================
    const int b = bid - BB;
    float* Xitem = (float*)pool;                          // 192
    float* qh = (float*)(pool + 192);                     // 192
    float* vhs = (float*)(pool + 384);                    // 128*49*4 = 25088
    float* scs = (float*)(pool + 25472);                  // 8*132*4 = 4224
    float* osm = (float*)(pool + 29696);                  // 192
    unsigned char* validf = (unsigned char*)(pool + 29888); // 128

    if (tid < 48) {
      const int seg = tid >> 4, e = tid & 15;
      const int id = (seg == 0) ? ig[b] : (seg == 1) ? ish[b] : ici[b];
      Xitem[tid] = emb[(size_t)id * 16 + e];
    }
    __syncthreads();
    if (tid < 48) {
      float a = sbq[tid];
      for (int e = 0; e < 48; ++e) a += Xitem[e] * sWq[e * 48 + tid];
      qh[tid] = a;
    }

    // wave w: role = w>>2, jh = (w>>1)&1, p = (w&1)*64 + lane
    const int role = wave >> 2;
    const int jh = (wave >> 1) & 1;
    const int p = ((wave & 1) << 6) | lane;
    const size_t off = (size_t)b * LSx + p;
    const int gid = sg[off], sid = ss[off], cid = scd[off];
    // barrier (qh visible) + count valid: one thread per p = waves 0-1
    const int nval = __syncthreads_count(tid < 128 && gid != 0);
    if (tid < 128) validf[p] = (unsigned char)(p < nval);  // mask = pos < slen

    const int j0 = __builtin_amdgcn_readfirstlane(jh * 24);
    float acc[24];
    if (role == 0) kv24(sWk, sbk, j0, gid, sid, cid, emb, acc);
    else           kv24(sWv, sbv, j0, gid, sid, cid, emb, acc);

    if (role == 0) {
      #pragma unroll
      for (int hh = 0; hh < 4; ++hh) {
        const int h = jh * 4 + hh;
        float s = 0.f;
        #pragma unroll
        for (int d = 0; d < 6; ++d) s += qh[h * 6 + d] * acc[hh * 6 + d];
        scs[h * 132 + p] = s * 0.40824829046386301637f;
      }
    } else {
      #pragma unroll
      for (int j = 0; j < 24; ++j) vhs[p * 49 + j0 + j] = acc[j];
    }
    __syncthreads();

    if (tid < 128) {
      const int h = tid >> 4, l16b = tid & 15;
      float amax = -INFINITY;
      for (int k = l16b; k < LSx; k += 16) if (validf[k]) amax = fmaxf(amax, scs[h * 132 + k]);
      #pragma unroll
      for (int m = 1; m < 16; m <<= 1) amax = fmaxf(amax, __shfl_xor(amax, m, 16));
      if (nval == 0) {
        for (int k = l16b; k < LSx; k += 16) scs[h * 132 + k] = 1.0f / (float)LSx;
      } else {
        float ssum = 0.f;
        for (int k = l16b; k < LSx; k += 16) {
          const float ev = validf[k] ? expf(scs[h * 132 + k] - amax) : 0.f;
          scs[h * 132 + k] = ev;
          ssum += ev;
        }
        #pragma unroll
        for (int m = 1; m < 16; m <<= 1) ssum += __shfl_xor(ssum, m, 16);
        const float inv = 1.0f / ssum;
        for (int k = l16b; k < LSx; k += 16) scs[h * 132 + k] *= inv;
      }
    }
    __syncthreads();

    if (tid < 48) {
      const int h = tid / 6;
      float a = 0.f;
      for (int k = 0; k < LSx; ++k) a += scs[h * 132 + k] * vhs[k * 49 + tid];
      osm[tid] = a;
    }
    __syncthreads();
    if (tid < 48) {
      float r = sbo[tid];
      for (int j = 0; j < 48; ++j) r += osm[j] * sWo[j * 48 + tid];
      sint[b * 48 + tid] = r;
    }
  }
}

// ---------------------------------------------------------------------------
// Kernel 3: MLP head (one block per batch elem)
// ---------------------------------------------------------------------------
__device__ __forceinline__ float block_sum256(float v, float* red) {
  #pragma unroll
  for (int m = 32; m >= 1; m >>= 1) v += __shfl_xor(v, m, 64);
  const int lane = threadIdx.x & 63, wave = threadIdx.x >> 6;
  if (lane == 0) red[wave] = v;
  __syncthreads();
  const float t = red[0] + red[1] + red[2] + red[3];
  __syncthreads();
  return t;
}

__global__ __launch_bounds__(256) void k_mlp(
    const int* __restrict__ uid, const int* __restrict__ u1, const int* __restrict__ u2,
    const int* __restrict__ u3, const int* __restrict__ u4,
    const int* __restrict__ ig, const int* __restrict__ ish, const int* __restrict__ ici,
    const float* __restrict__ emb,
    const float* __restrict__ sint, const float* __restrict__ lint,
    const float* __restrict__ W1, const float* __restrict__ b1,
    const float* __restrict__ g1, const float* __restrict__ be1,
    const float* __restrict__ W2, const float* __restrict__ b2,
    const float* __restrict__ g2, const float* __restrict__ be2,
    const float* __restrict__ W3, const float* __restrict__ b3,
    float* __restrict__ out)
{
  __shared__ __align__(16) float x[224];
  __shared__ __align__(16) float h1[200];
  __shared__ float h2[80];
  __shared__ float red[4];
  const int b = blockIdx.x, tid = threadIdx.x;

  if (tid < 128) {
    const int e = tid & 15;
    int id;
    if (tid < 48) {
      const int seg = tid >> 4;
      id = (seg == 0) ? ig[b] : (seg == 1) ? ish[b] : ici[b];
    } else {
      const int f = (tid - 48) >> 4;
      id = (f == 0) ? uid[b] : (f == 1) ? u1[b] : (f == 2) ? u2[b] : (f == 3) ? u3[b] : u4[b];
    }
    x[tid] = emb[(size_t)id * 16 + e];
  } else if (tid < 176) {
    x[tid] = sint[b * 48 + (tid - 128)];
  } else if (tid < 224) {
    x[tid] = lint[b * 48 + (tid - 176)];
  }
  __syncthreads();

  float v = 0.f;
  if (tid < 200) {
    float a0 = b1[tid], a1 = 0.f, a2 = 0.f, a3 = 0.f;
    for (int i4 = 0; i4 < 56; ++i4) {
      const float4 xv = *(const float4*)(x + i4 * 4);
      const float* w = W1 + i4 * 4 * 200 + tid;
      a0 += xv.x * w[0];
      a1 += xv.y * w[200];
      a2 += xv.z * w[400];
      a3 += xv.w * w[600];
    }
    v = (a0 + a1) + (a2 + a3);
  }
  const float mean1 = block_sum256((tid < 200) ? v : 0.f, red) * (1.0f / 200.0f);
  const float dv = (tid < 200) ? (v - mean1) : 0.f;
  const float var1 = block_sum256(dv * dv, red) * (1.0f / 200.0f);
  if (tid < 200) {
    const float y = (v - mean1) * rsqrtf(var1 + 1e-3f) * g1[tid] + be1[tid];
    h1[tid] = fmaxf(y, 0.f);
  }
  __syncthreads();

  float v2 = 0.f;
  if (tid < 80) {
    float a0 = b2[tid], a1 = 0.f, a2 = 0.f, a3 = 0.f;
    for (int i4 = 0; i4 < 50; ++i4) {
      const float4 xv = *(const float4*)(h1 + i4 * 4);
      const float* w = W2 + i4 * 4 * 80 + tid;
      a0 += xv.x * w[0];
      a1 += xv.y * w[80];
      a2 += xv.z * w[160];
      a3 += xv.w * w[240];
    }
    v2 = (a0 + a1) + (a2 + a3);
  }
  const float mean2 = block_sum256((tid < 80) ? v2 : 0.f, red) * (1.0f / 80.0f);
  const float dv2 = (tid < 80) ? (v2 - mean2) : 0.f;
  const float var2 = block_sum256(dv2 * dv2, red) * (1.0f / 80.0f);
  if (tid < 80) {
    const float y = (v2 - mean2) * rsqrtf(var2 + 1e-3f) * g2[tid] + be2[tid];
    h2[tid] = fmaxf(y, 0.f);
  }
  __syncthreads();

  const float p = (tid < 80) ? h2[tid] * W3[tid] : 0.f;
  const float z = block_sum256(p, red);
  if (tid == 0) {
    out[b] = 1.0f / (1.0f + expf(-(z + b3[0])));
  }
}

// ---------------------------------------------------------------------------
extern "C" void kernel_launch(void* const* d_in, const int* in_sizes, int n_in,
                              void* d_out, int out_size, void* d_ws, size_t ws_size,
                              hipStream_t stream) {
  (void)in_sizes; (void)n_in; (void)out_size; (void)ws_size;
  const int* uid = (const int*)d_in[0];
  const int* u1  = (const int*)d_in[1];
  const int* u2  = (const int*)d_in[2];
  const int* u3  = (const int*)d_in[3];
  const int* u4  = (const int*)d_in[4];
  const int* ig  = (const int*)d_in[5];
  const int* ish = (const int*)d_in[6];
  const int* ici = (const int*)d_in[7];
  const int* sg  = (const int*)d_in[8];
  const int* ss  = (const int*)d_in[9];
  const int* scd = (const int*)d_in[10];
  const int* lg  = (const int*)d_in[11];
  const int* ls  = (const int*)d_in[12];
  const int* lcd = (const int*)d_in[13];
  const float* emb = (const float*)d_in[14];
  const float* Hm  = (const float*)d_in[15];
  const float* sWq = (const float*)d_in[16];
  const float* sbq = (const float*)d_in[17];
  const float* sWk = (const float*)d_in[18];
  const float* sbk = (const float*)d_in[19];
  const float* sWv = (const float*)d_in[20];
  const float* sbv = (const float*)d_in[21];
  const float* sWo = (const float*)d_in[22];
  const float* sbo = (const float*)d_in[23];
  const float* lWq = (const float*)d_in[24];
  const float* lbq = (const float*)d_in[25];
  const float* lWk = (const float*)d_in[26];
  const float* lbk = (const float*)d_in[27];
  const float* lWv = (const float*)d_in[28];
  const float* lbv = (const float*)d_in[29];
  const float* lWo = (const float*)d_in[30];
  const float* lbo = (const float*)d_in[31];
  const float* W1 = (const float*)d_in[32];
  const float* b1 = (const float*)d_in[33];
  const float* g1 = (const float*)d_in[34];
  const float* be1 = (const float*)d_in[35];
  const float* W2 = (const float*)d_in[36];
  const float* b2 = (const float*)d_in[37];
  const float* g2 = (const float*)d_in[38];
  const float* be2 = (const float*)d_in[39];
  const float* W3 = (const float*)d_in[40];
  const float* b3 = (const float*)d_in[41];
  float* out = (float*)d_out;

  float* sint = (float*)d_ws;                  // 196,608 B
  float* lint = sint + BB * 48;                // 196,608 B
  __half* Ph = (__half*)(lint + BB * 48);      // 15,360,000 B (total ~15.8 MB)

  k_partial<<<dim3((VOCABx + 255) / 256), dim3(256), 0, stream>>>(emb, Hm, Ph);
  k_main<<<dim3(2 * BB), dim3(512), 0, stream>>>(
      lg, ls, lcd, sg, ss, scd, ig, ish, ici, emb, Hm, Ph,
      sWq, sbq, sWk, sbk, sWv, sbv, sWo, sbo,
      lWq, lbq, lWk, lbk, lWv, lbv, lWo, lbo,
      sint, lint);
  k_mlp<<<dim3(BB), dim3(256), 0, stream>>>(
      uid, u1, u2, u3, u4, ig, ish, ici, emb,
      sint, lint, W1, b1, g1, be1, W2, b2, g2, be2, W3, b3, out);
}

// Round 5
// 336.337 us; speedup vs baseline: 2.6361x; 2.6361x over previous
//
#include <hip/hip_runtime.h>
#include <hip/hip_fp16.h>
#include <math.h>

#define BB 1024
#define LSx 128
#define LLx 2048
#define TOPKx 48
#define VOCABx 160000

// ---------------------------------------------------------------------------
// Kernel A: precompute partial LSH projections (fp16 storage), thread per v.
//   Ph[v][seg][m] = sum_e emb[v][e] * H[seg*16+e][m]
// ---------------------------------------------------------------------------
__global__ __launch_bounds__(256) void k_partial(
    const float* __restrict__ emb, const float* __restrict__ Hm,
    __half* __restrict__ Ph)
{
  const int v = blockIdx.x * 256 + threadIdx.x;
  if (v >= VOCABx) return;
  const float4* er = (const float4*)(emb + (size_t)v * 16);
  const float4 x0 = er[0], x1 = er[1], x2 = er[2], x3 = er[3];
  const float x[16] = {x0.x, x0.y, x0.z, x0.w, x1.x, x1.y, x1.z, x1.w,
                       x2.x, x2.y, x2.z, x2.w, x3.x, x3.y, x3.z, x3.w};
  unsigned int packed[24];
  #pragma unroll
  for (int seg = 0; seg < 3; ++seg) {
    #pragma unroll
    for (int mp = 0; mp < 8; ++mp) {
      float a0 = 0.f, a1 = 0.f;
      #pragma unroll
      for (int e = 0; e < 16; ++e) {
        a0 += x[e] * Hm[(seg * 16 + e) * 16 + 2 * mp];
        a1 += x[e] * Hm[(seg * 16 + e) * 16 + 2 * mp + 1];
      }
      const __half2 hp = __floats2half2_rn(a0, a1);
      packed[seg * 8 + mp] = *(const unsigned int*)&hp;
    }
  }
  uint4* dst = (uint4*)(Ph + (size_t)v * 48);
  #pragma unroll
  for (int q = 0; q < 6; ++q) {
    uint4 o;
    o.x = packed[q * 4 + 0]; o.y = packed[q * 4 + 1];
    o.z = packed[q * 4 + 2]; o.w = packed[q * 4 + 3];
    dst[q] = o;
  }
}

// ---------------------------------------------------------------------------
// Kernel B: LSH scoring + top-k. 512 threads; 16-lane group per position,
// 8 positions in flight per thread; ballot score; writes sel to global.
// ---------------------------------------------------------------------------
__global__ __launch_bounds__(512) void k_score_topk(
    const int* __restrict__ lg, const int* __restrict__ lsh, const int* __restrict__ lc,
    const int* __restrict__ ig, const int* __restrict__ ish, const int* __restrict__ ici,
    const float* __restrict__ emb, const float* __restrict__ Hm,
    const __half* __restrict__ Ph,
    int* __restrict__ sel)
{
  __shared__ int idsL[3 * LLx];          // 24 KB
  __shared__ signed char scores[LLx];    // 2 KB
  __shared__ float Xitem[48];
  __shared__ int icodeS[16];
  __shared__ int hist[18];
  __shared__ int cnt_above;
  __shared__ int wsum[8];
  const int b = blockIdx.x, tid = threadIdx.x;
  const int lane = tid & 63, wave = tid >> 6;

  ((int4*)idsL)[tid]        = ((const int4*)(lg  + (size_t)b * LLx))[tid];
  ((int4*)idsL)[512 + tid]  = ((const int4*)(lsh + (size_t)b * LLx))[tid];
  ((int4*)idsL)[1024 + tid] = ((const int4*)(lc  + (size_t)b * LLx))[tid];
  if (tid < 48) {
    const int seg = tid >> 4, e = tid & 15;
    const int id = (seg == 0) ? ig[b] : (seg == 1) ? ish[b] : ici[b];
    Xitem[tid] = emb[(size_t)id * 16 + e];
  }
  if (tid < 18) hist[tid] = 0;
  if (tid == 0) cnt_above = 0;
  __syncthreads();
  if (tid < 16) {  // exact fp32 item code
    float dd = 0.f;
    for (int e = 0; e < 48; ++e) dd += Xitem[e] * Hm[e * 16 + tid];
    icodeS[tid] = (dd > 0.f) ? 1 : (dd < 0.f ? -1 : 0);
  }
  __syncthreads();

  const int l16 = tid & 15;
  const int grpw = (tid >> 4) & 3;
  const int grp32 = tid >> 4;
  const int myic = icodeS[l16];

  for (int r8 = 0; r8 < 64; r8 += 8) {
    int g_[8], s_[8], c_[8];
    #pragma unroll
    for (int u = 0; u < 8; ++u) {
      const int p = (r8 + u) * 32 + grp32;
      g_[u] = idsL[p]; s_[u] = idsL[LLx + p]; c_[u] = idsL[2 * LLx + p];
    }
    float d0[8], d1[8], d2[8];
    #pragma unroll
    for (int u = 0; u < 8; ++u) {
      d0[u] = __half2float(Ph[(size_t)g_[u] * 48 + l16]);
      d1[u] = __half2float(Ph[(size_t)s_[u] * 48 + 16 + l16]);
      d2[u] = __half2float(Ph[(size_t)c_[u] * 48 + 32 + l16]);
    }
    #pragma unroll
    for (int u = 0; u < 8; ++u) {
      const int p = (r8 + u) * 32 + grp32;
      const float d = (d0[u] + d1[u]) + d2[u];
      const int cs = (d > 0.f) ? 1 : (d < 0.f ? -1 : 0);
      const unsigned long long bal = __ballot(cs == myic);
      int sc = (int)__popcll((bal >> (16 * grpw)) & 0xFFFFull);
      if (g_[u] == 0) sc = -1;   // masked (reference: -inf)
      if (l16 == 0) {
        scores[p] = (signed char)sc;
        atomicAdd(&hist[sc + 1], 1);
      }
    }
  }
  __syncthreads();

  // ---- threshold (identical on all threads) ----
  int above = 0, tval = -1, need = 0;
  for (int s = 16; s >= -1; --s) {
    const int c = hist[s + 1];
    if (above + c >= TOPKx) { tval = s; need = TOPKx - above; break; }
    above += c;
  }

  // ---- tie ranking: 4 consecutive positions per thread + block scan ----
  const int base_l = tid * 4;
  int myscore[4];
  #pragma unroll
  for (int j = 0; j < 4; ++j) myscore[j] = scores[base_l + j];
  int cnt = 0;
  #pragma unroll
  for (int j = 0; j < 4; ++j) cnt += (myscore[j] == tval) ? 1 : 0;
  int v = cnt;
  #pragma unroll
  for (int o = 1; o < 64; o <<= 1) {
    const int u = __shfl_up(v, o, 64);
    if (lane >= o) v += u;
  }
  if (lane == 63) wsum[wave] = v;
  __syncthreads();
  int rank = v - cnt;
  for (int w = 0; w < wave; ++w) rank += wsum[w];

  #pragma unroll
  for (int j = 0; j < 4; ++j) {
    const int l = base_l + j;
    const int s = myscore[j];
    if (s > tval) {
      const int slot = atomicAdd(&cnt_above, 1);
      sel[b * TOPKx + slot] = l;
    } else if (s == tval) {
      if (rank < need) sel[b * TOPKx + above + rank] = l;
      ++rank;
    }
  }
}

// ---------------------------------------------------------------------------
// MHA body (R0 shape): one thread per key position computes kh AND vh.
// Weight pointers are compile-time distinct per inline site -> s_load.
// ---------------------------------------------------------------------------
template<int K, int STRIDE, bool IS_LONG>
__device__ __forceinline__ void mha_body(
    int b, char* pool,
    const int* __restrict__ kg, const int* __restrict__ ks, const int* __restrict__ kc,
    const int* __restrict__ ig, const int* __restrict__ ish, const int* __restrict__ ici,
    const float* __restrict__ emb,
    const float* __restrict__ Wq, const float* __restrict__ bq,
    const float* __restrict__ Wk, const float* __restrict__ bk,
    const float* __restrict__ Wv, const float* __restrict__ bv,
    const float* __restrict__ Wo, const float* __restrict__ bo,
    const int* __restrict__ sel,
    float* __restrict__ outv)
{
  float* vhs = (float*)pool;                                   // K*48*4
  float* scs = (float*)(pool + K * 48 * 4);                    // 8*(K+4)*4
  float* Xitem = (float*)(pool + K * 48 * 4 + 8 * (K + 4) * 4);          // 192
  float* qh = Xitem + 48;                                                // 192
  float* osm = qh + 48;                                                  // 192
  unsigned char* validf = (unsigned char*)(osm + 48);                    // K
  const int tid = threadIdx.x;

  if (tid < 48) {
    const int seg = tid >> 4, e = tid & 15;
    const int id = (seg == 0) ? ig[b] : (seg == 1) ? ish[b] : ici[b];
    Xitem[tid] = emb[(size_t)id * 16 + e];
  }
  __syncthreads();
  if (tid < 48) {
    float a = bq[tid];
    for (int e = 0; e < 48; ++e) a += Xitem[e] * Wq[e * 48 + tid];
    qh[tid] = a;
  }

  int gid = 0, sid = 0, cid = 0;
  if (tid < K) {
    const int pos = IS_LONG ? sel[b * TOPKx + tid] : tid;
    const size_t off = (size_t)b * STRIDE + pos;
    gid = kg[off]; sid = ks[off]; cid = kc[off];
  }
  // barrier (qh now visible) + count valid
  const int nval = __syncthreads_count((tid < K) && (gid != 0));

  if (tid < K) {
    // short: mask is position < slen; long: mask is gid != 0 on selected
    validf[tid] = IS_LONG ? (unsigned char)(gid != 0) : (unsigned char)(tid < nval);
    float kh[48], vh[48];
    #pragma unroll
    for (int j = 0; j < 48; ++j) { kh[j] = bk[j]; vh[j] = bv[j]; }
    const int ids3[3] = {gid, sid, cid};
    #pragma unroll
    for (int seg = 0; seg < 3; ++seg) {
      const float* row = emb + (size_t)ids3[seg] * 16;
      #pragma unroll
      for (int i4 = 0; i4 < 4; ++i4) {
        const float4 xv = ((const float4*)row)[i4];
        const float xs[4] = {xv.x, xv.y, xv.z, xv.w};
        #pragma unroll
        for (int c = 0; c < 4; ++c) {
          const int e = seg * 16 + i4 * 4 + c;
          const float* wkr = Wk + e * 48;
          const float* wvr = Wv + e * 48;
          const float xe = xs[c];
          #pragma unroll
          for (int j = 0; j < 48; ++j) {
            kh[j] += xe * wkr[j];
            vh[j] += xe * wvr[j];
          }
        }
      }
    }
    #pragma unroll
    for (int h = 0; h < 8; ++h) {
      float s = 0.f;
      #pragma unroll
      for (int d = 0; d < 6; ++d) s += qh[h * 6 + d] * kh[h * 6 + d];
      scs[h * (K + 4) + tid] = s * 0.40824829046386301637f;   // 1/sqrt(6)
    }
    #pragma unroll
    for (int j = 0; j < 48; ++j) vhs[tid * 48 + j] = vh[j];
  }
  __syncthreads();

  // ---- softmax: 8 groups of 16 lanes, one head each ----
  {
    const int h = tid >> 4, l16 = tid & 15;
    float amax = -INFINITY;
    for (int k = l16; k < K; k += 16) if (validf[k]) amax = fmaxf(amax, scs[h * (K + 4) + k]);
    #pragma unroll
    for (int m = 1; m < 16; m <<= 1) amax = fmaxf(amax, __shfl_xor(amax, m, 16));
    if (nval == 0) {
      // reference: all entries get -1e9 -> fp32 rounds equal -> uniform weights
      for (int k = l16; k < K; k += 16) scs[h * (K + 4) + k] = 1.0f / (float)K;
    } else {
      float ssum = 0.f;
      for (int k = l16; k < K; k += 16) {
        const float ev = validf[k] ? expf(scs[h * (K + 4) + k] - amax) : 0.f;
        scs[h * (K + 4) + k] = ev;
        ssum += ev;
      }
      #pragma unroll
      for (int m = 1; m < 16; m <<= 1) ssum += __shfl_xor(ssum, m, 16);
      const float inv = 1.0f / ssum;
      for (int k = l16; k < K; k += 16) scs[h * (K + 4) + k] *= inv;
    }
  }
  __syncthreads();

  if (tid < 48) {
    const int h = tid / 6;
    float a = 0.f;
    for (int k = 0; k < K; ++k) a += scs[h * (K + 4) + k] * vhs[k * 48 + tid];
    osm[tid] = a;
  }
  __syncthreads();
  if (tid < 48) {
    float r = bo[tid];
    for (int j = 0; j < 48; ++j) r += osm[j] * Wo[j * 48 + tid];
    outv[b * 48 + tid] = r;
  }
}

// Merged MHA: bid < BB -> short, else long. One launch, block-uniform branch.
__global__ __launch_bounds__(128) void k_mha_all(
    const int* __restrict__ sg, const int* __restrict__ ss, const int* __restrict__ scd,
    const int* __restrict__ lg, const int* __restrict__ ls, const int* __restrict__ lcd,
    const int* __restrict__ ig, const int* __restrict__ ish, const int* __restrict__ ici,
    const float* __restrict__ emb,
    const float* __restrict__ sWq, const float* __restrict__ sbq,
    const float* __restrict__ sWk, const float* __restrict__ sbk,
    const float* __restrict__ sWv, const float* __restrict__ sbv,
    const float* __restrict__ sWo, const float* __restrict__ sbo,
    const float* __restrict__ lWq, const float* __restrict__ lbq,
    const float* __restrict__ lWk, const float* __restrict__ lbk,
    const float* __restrict__ lWv, const float* __restrict__ lbv,
    const float* __restrict__ lWo, const float* __restrict__ lbo,
    const int* __restrict__ sel,
    float* __restrict__ sint, float* __restrict__ lint)
{
  // max(short, long) LDS: short = 128*48*4 + 8*132*4 + 3*192 + 128 = 29.6 KB
  __shared__ __align__(16) char pool[29888];
  const int bid = blockIdx.x;
  if (bid < BB) {
    mha_body<LSx, LSx, false>(bid, pool, sg, ss, scd, ig, ish, ici, emb,
                              sWq, sbq, sWk, sbk, sWv, sbv, sWo, sbo,
                              (const int*)nullptr, sint);
  } else {
    mha_body<TOPKx, LLx, true>(bid - BB, pool, lg, ls, lcd, ig, ish, ici, emb,
                               lWq, lbq, lWk, lbk, lWv, lbv, lWo, lbo,
                               sel, lint);
  }
}

// ---------------------------------------------------------------------------
// Kernel 3: MLP head (one block per batch elem)
// ---------------------------------------------------------------------------
__device__ __forceinline__ float block_sum256(float v, float* red) {
  #pragma unroll
  for (int m = 32; m >= 1; m >>= 1) v += __shfl_xor(v, m, 64);
  const int lane = threadIdx.x & 63, wave = threadIdx.x >> 6;
  if (lane == 0) red[wave] = v;
  __syncthreads();
  const float t = red[0] + red[1] + red[2] + red[3];
  __syncthreads();
  return t;
}

__global__ __launch_bounds__(256) void k_mlp(
    const int* __restrict__ uid, const int* __restrict__ u1, const int* __restrict__ u2,
    const int* __restrict__ u3, const int* __restrict__ u4,
    const int* __restrict__ ig, const int* __restrict__ ish, const int* __restrict__ ici,
    const float* __restrict__ emb,
    const float* __restrict__ sint, const float* __restrict__ lint,
    const float* __restrict__ W1, const float* __restrict__ b1,
    const float* __restrict__ g1, const float* __restrict__ be1,
    const float* __restrict__ W2, const float* __restrict__ b2,
    const float* __restrict__ g2, const float* __restrict__ be2,
    const float* __restrict__ W3, const float* __restrict__ b3,
    float* __restrict__ out)
{
  __shared__ __align__(16) float x[224];
  __shared__ __align__(16) float h1[200];
  __shared__ float h2[80];
  __shared__ float red[4];
  const int b = blockIdx.x, tid = threadIdx.x;

  if (tid < 128) {
    const int e = tid & 15;
    int id;
    if (tid < 48) {
      const int seg = tid >> 4;
      id = (seg == 0) ? ig[b] : (seg == 1) ? ish[b] : ici[b];
    } else {
      const int f = (tid - 48) >> 4;
      id = (f == 0) ? uid[b] : (f == 1) ? u1[b] : (f == 2) ? u2[b] : (f == 3) ? u3[b] : u4[b];
    }
    x[tid] = emb[(size_t)id * 16 + e];
  } else if (tid < 176) {
    x[tid] = sint[b * 48 + (tid - 128)];
  } else if (tid < 224) {
    x[tid] = lint[b * 48 + (tid - 176)];
  }
  __syncthreads();

  float v = 0.f;
  if (tid < 200) {
    float a0 = b1[tid], a1 = 0.f, a2 = 0.f, a3 = 0.f;
    for (int i4 = 0; i4 < 56; ++i4) {
      const float4 xv = *(const float4*)(x + i4 * 4);
      const float* w = W1 + i4 * 4 * 200 + tid;
      a0 += xv.x * w[0];
      a1 += xv.y * w[200];
      a2 += xv.z * w[400];
      a3 += xv.w * w[600];
    }
    v = (a0 + a1) + (a2 + a3);
  }
  const float mean1 = block_sum256((tid < 200) ? v : 0.f, red) * (1.0f / 200.0f);
  const float dv = (tid < 200) ? (v - mean1) : 0.f;
  const float var1 = block_sum256(dv * dv, red) * (1.0f / 200.0f);
  if (tid < 200) {
    const float y = (v - mean1) * rsqrtf(var1 + 1e-3f) * g1[tid] + be1[tid];
    h1[tid] = fmaxf(y, 0.f);
  }
  __syncthreads();

  float v2 = 0.f;
  if (tid < 80) {
    float a0 = b2[tid], a1 = 0.f, a2 = 0.f, a3 = 0.f;
    for (int i4 = 0; i4 < 50; ++i4) {
      const float4 xv = *(const float4*)(h1 + i4 * 4);
      const float* w = W2 + i4 * 4 * 80 + tid;
      a0 += xv.x * w[0];
      a1 += xv.y * w[80];
      a2 += xv.z * w[160];
      a3 += xv.w * w[240];
    }
    v2 = (a0 + a1) + (a2 + a3);
  }
  const float mean2 = block_sum256((tid < 80) ? v2 : 0.f, red) * (1.0f / 80.0f);
  const float dv2 = (tid < 80) ? (v2 - mean2) : 0.f;
  const float var2 = block_sum256(dv2 * dv2, red) * (1.0f / 80.0f);
  if (tid < 80) {
    const float y = (v2 - mean2) * rsqrtf(var2 + 1e-3f) * g2[tid] + be2[tid];
    h2[tid] = fmaxf(y, 0.f);
  }
  __syncthreads();

  const float p = (tid < 80) ? h2[tid] * W3[tid] : 0.f;
  const float z = block_sum256(p, red);
  if (tid == 0) {
    out[b] = 1.0f / (1.0f + expf(-(z + b3[0])));
  }
}

// ---------------------------------------------------------------------------
extern "C" void kernel_launch(void* const* d_in, const int* in_sizes, int n_in,
                              void* d_out, int out_size, void* d_ws, size_t ws_size,
                              hipStream_t stream) {
  (void)in_sizes; (void)n_in; (void)out_size; (void)ws_size;
  const int* uid = (const int*)d_in[0];
  const int* u1  = (const int*)d_in[1];
  const int* u2  = (const int*)d_in[2];
  const int* u3  = (const int*)d_in[3];
  const int* u4  = (const int*)d_in[4];
  const int* ig  = (const int*)d_in[5];
  const int* ish = (const int*)d_in[6];
  const int* ici = (const int*)d_in[7];
  const int* sg  = (const int*)d_in[8];
  const int* ss  = (const int*)d_in[9];
  const int* scd = (const int*)d_in[10];
  const int* lg  = (const int*)d_in[11];
  const int* ls  = (const int*)d_in[12];
  const int* lcd = (const int*)d_in[13];
  const float* emb = (const float*)d_in[14];
  const float* Hm  = (const float*)d_in[15];
  const float* sWq = (const float*)d_in[16];
  const float* sbq = (const float*)d_in[17];
  const float* sWk = (const float*)d_in[18];
  const float* sbk = (const float*)d_in[19];
  const float* sWv = (const float*)d_in[20];
  const float* sbv = (const float*)d_in[21];
  const float* sWo = (const float*)d_in[22];
  const float* sbo = (const float*)d_in[23];
  const float* lWq = (const float*)d_in[24];
  const float* lbq = (const float*)d_in[25];
  const float* lWk = (const float*)d_in[26];
  const float* lbk = (const float*)d_in[27];
  const float* lWv = (const float*)d_in[28];
  const float* lbv = (const float*)d_in[29];
  const float* lWo = (const float*)d_in[30];
  const float* lbo = (const float*)d_in[31];
  const float* W1 = (const float*)d_in[32];
  const float* b1 = (const float*)d_in[33];
  const float* g1 = (const float*)d_in[34];
  const float* be1 = (const float*)d_in[35];
  const float* W2 = (const float*)d_in[36];
  const float* b2 = (const float*)d_in[37];
  const float* g2 = (const float*)d_in[38];
  const float* be2 = (const float*)d_in[39];
  const float* W3 = (const float*)d_in[40];
  const float* b3 = (const float*)d_in[41];
  float* out = (float*)d_out;

  int* sel = (int*)d_ws;                       //  196,608 B
  float* sint = (float*)d_ws + BB * TOPKx;     //  196,608 B
  float* lint = sint + BB * 48;                //  196,608 B
  __half* Ph = (__half*)(lint + BB * 48);      // 15,360,000 B (total ~15.9 MB)

  k_partial<<<dim3((VOCABx + 255) / 256), dim3(256), 0, stream>>>(emb, Hm, Ph);
  k_score_topk<<<dim3(BB), dim3(512), 0, stream>>>(lg, ls, lcd, ig, ish, ici, emb, Hm, Ph, sel);
  k_mha_all<<<dim3(2 * BB), dim3(128), 0, stream>>>(
      sg, ss, scd, lg, ls, lcd, ig, ish, ici, emb,
      sWq, sbq, sWk, sbk, sWv, sbv, sWo, sbo,
      lWq, lbq, lWk, lbk, lWv, lbv, lWo, lbo,
      sel, sint, lint);
  k_mlp<<<dim3(BB), dim3(256), 0, stream>>>(
      uid, u1, u2, u3, u4, ig, ish, ici, emb,
      sint, lint, W1, b1, g1, be1, W2, b2, g2, be2, W3, b3, out);
}